// Round 3
// baseline (211.604 us; speedup 1.0000x reference)
//
#include <hip/hip_runtime.h>
#include <hip/hip_bf16.h>

#define NTOK 2048      // B*T
#define DM 1024
#define NEXP 8
#define FFN 4096
#define BK 64
#define BM 256
#define BN 64
#define ASTR 72        // LDS row stride (bf16): 144B, 16B-aligned, read-conflict-free
#define G2_SPLIT 4

typedef __bf16 bf16x8 __attribute__((ext_vector_type(8)));
typedef __bf16 bf16x4 __attribute__((ext_vector_type(4)));
typedef float f32x4 __attribute__((ext_vector_type(4)));

__device__ __forceinline__ bf16x8 zero8() {
  bf16x8 z;
#pragma unroll
  for (int j = 0; j < 8; j++) z[j] = (__bf16)0.f;
  return z;
}

// 4x4 f32 transpose across lanes {l, l^16, l^32, l^48}.
// In: lane quad q holds row q: v[i] = M[q][i].  Out: v[i] = M[i][q].
__device__ __forceinline__ void xpose4(float v[4], int quad) {
  const bool b0 = quad & 1;
  const bool b1 = (quad & 2) != 0;
  float t;
  t = __shfl_xor(b0 ? v[0] : v[1], 16, 64); if (b0) v[0] = t; else v[1] = t;
  t = __shfl_xor(b0 ? v[2] : v[3], 16, 64); if (b0) v[2] = t; else v[3] = t;
  t = __shfl_xor(b1 ? v[0] : v[2], 32, 64); if (b1) v[0] = t; else v[2] = t;
  t = __shfl_xor(b1 ? v[1] : v[3], 32, 64); if (b1) v[1] = t; else v[3] = t;
}

// ---------------- router + bf16 compact gather ----------------
__global__ __launch_bounds__(256) void router_gather(
    const float* __restrict__ x, const int* __restrict__ mask,
    const float* __restrict__ rw, int* __restrict__ counts,
    int* __restrict__ tlist, float* __restrict__ gateE,
    __bf16* __restrict__ xg)
{
  int wid = threadIdx.x >> 6, lane = threadIdx.x & 63;
  int t = blockIdx.x * 4 + wid;

  const float* xr = x + (size_t)t * DM;
  float xv[16];
#pragma unroll
  for (int i = 0; i < 4; i++) {
    const float4 v = *(const float4*)(xr + lane * 16 + i * 4);
    xv[i * 4 + 0] = v.x; xv[i * 4 + 1] = v.y;
    xv[i * 4 + 2] = v.z; xv[i * 4 + 3] = v.w;
  }

  float acc[NEXP];
#pragma unroll
  for (int e = 0; e < NEXP; e++) {
    float a = 0.f;
    const float* rwe = rw + e * DM + lane * 16;
#pragma unroll
    for (int i = 0; i < 4; i++) {
      const float4 r = *(const float4*)(rwe + i * 4);
      a += xv[i*4+0]*r.x + xv[i*4+1]*r.y + xv[i*4+2]*r.z + xv[i*4+3]*r.w;
    }
    acc[e] = a;
  }
#pragma unroll
  for (int e = 0; e < NEXP; e++)
#pragma unroll
    for (int s = 1; s < 64; s <<= 1) acc[e] += __shfl_xor(acc[e], s, 64);

  int pack = -1;
  if (lane == 0 && mask[t] != 0) {
    float m = acc[0]; int am = 0;
#pragma unroll
    for (int e = 1; e < NEXP; e++) if (acc[e] > m) { m = acc[e]; am = e; }
    float s = 0.f;
#pragma unroll
    for (int e = 0; e < NEXP; e++) s += __expf(acc[e] - m);
    int slot = atomicAdd(&counts[am], 1);
    tlist[am * NTOK + slot] = t;
    gateE[am * NTOK + slot] = 1.0f / s;   // softmax prob of argmax
    pack = am * NTOK + slot;
  }
  pack = __shfl(pack, 0, 64);
  if (pack >= 0) {
    __bf16* dst = xg + (size_t)pack * DM + lane * 16;
    bf16x8 o0, o1;
#pragma unroll
    for (int j = 0; j < 8; j++) {
      o0[j] = (__bf16)xv[j];
      o1[j] = (__bf16)xv[8 + j];
    }
    *(bf16x8*)dst = o0;
    *(bf16x8*)(dst + 8) = o1;
  }
}

// ---------------- GEMM1: h[tok] = relu(xg_e @ w1[e]) ----------------
__global__ __launch_bounds__(256) void moe_gemm1(
    const __bf16* __restrict__ xg, const float* __restrict__ w1,
    const int* __restrict__ counts, const int* __restrict__ tlist,
    __bf16* __restrict__ h)
{
  int bx = blockIdx.x;
  int nt = bx & 63, mt = (bx >> 6) & 7, e = bx >> 9;
  int cnt = counts[e];
  int m0 = mt * BM;
  if (m0 >= cnt) return;
  int n0 = nt * BN;

  __shared__ __bf16 As[BM][ASTR];
  __shared__ __bf16 Bs[BN][ASTR];
  __shared__ int toks[BM];

  int tid = threadIdx.x;
  int lane = tid & 63, w = tid >> 6;
  int wm = w >> 1, wn = w & 1;
  int r16 = lane & 15, quad = lane >> 4;

  const __bf16* xge = xg + (size_t)e * NTOK * DM;
  const float* w1e = w1 + (size_t)e * DM * FFN;

  f32x4 acc[8][2] = {};

  for (int kb = 0; kb < DM; kb += BK) {
    // A: linear bf16 copy from compact gathered rows
#pragma unroll
    for (int it = 0; it < 8; it++) {
      int q = it * 256 + tid;
      int r = q >> 3, k8 = (q & 7) << 3;
      bf16x8 v = (m0 + r < cnt)
          ? *(const bf16x8*)(xge + (size_t)(m0 + r) * DM + kb + k8)
          : zero8();
      *(bf16x8*)&As[r][k8] = v;
    }
    // B: fp32 [k][n] -> register 4x4 transpose -> bf16 [n][k] LDS
#pragma unroll
    for (int it = 0; it < 4; it++) {
      int k = kb + it * 16 + w * 4 + quad;
      const float4 t4 = *(const float4*)(w1e + (size_t)k * FFN + n0 + r16 * 4);
      float vv[4] = {t4.x, t4.y, t4.z, t4.w};
      xpose4(vv, quad);
      bf16x4 o;
#pragma unroll
      for (int j = 0; j < 4; j++) o[j] = (__bf16)vv[j];
      *(bf16x4*)&Bs[r16 * 4 + quad][it * 16 + w * 4] = o;
    }
    __syncthreads();
#pragma unroll
    for (int kh = 0; kh < 2; kh++) {
      int ks = kh * 32 + quad * 8;
      bf16x8 b0 = *(const bf16x8*)&Bs[wn * 32 + r16][ks];
      bf16x8 b1 = *(const bf16x8*)&Bs[wn * 32 + 16 + r16][ks];
#pragma unroll
      for (int mf = 0; mf < 8; mf++) {
        bf16x8 a = *(const bf16x8*)&As[wm * 128 + mf * 16 + r16][ks];
        acc[mf][0] = __builtin_amdgcn_mfma_f32_16x16x32_bf16(a, b0, acc[mf][0], 0, 0, 0);
        acc[mf][1] = __builtin_amdgcn_mfma_f32_16x16x32_bf16(a, b1, acc[mf][1], 0, 0, 0);
      }
    }
    __syncthreads();
  }

  toks[tid] = (m0 + tid < cnt) ? tlist[e * NTOK + m0 + tid] : -1;
  __syncthreads();

#pragma unroll
  for (int mf = 0; mf < 8; mf++) {
#pragma unroll
    for (int i = 0; i < 4; i++) {
      int row = wm * 128 + mf * 16 + quad * 4 + i;
      int tok = toks[row];
      if (tok >= 0) {
        __bf16* hp = h + (size_t)tok * FFN + n0 + wn * 32 + r16;
        hp[0]  = (__bf16)fmaxf(acc[mf][0][i], 0.f);
        hp[16] = (__bf16)fmaxf(acc[mf][1][i], 0.f);
      }
    }
  }
}

// ------- GEMM2 (split-K): out[tok] += (h_e @ w2[e]) * gate ----------
__global__ __launch_bounds__(256) void moe_gemm2(
    const __bf16* __restrict__ h, const float* __restrict__ w2,
    const int* __restrict__ counts, const int* __restrict__ tlist,
    const float* __restrict__ gateE, float* __restrict__ out)
{
  int bx = blockIdx.x;
  int nt = bx & 15, mt = (bx >> 4) & 7, e = (bx >> 7) & 7, sp = bx >> 10;
  int cnt = counts[e];
  int m0 = mt * BM;
  if (m0 >= cnt) return;
  int n0 = nt * BN;
  int ksp = sp * (FFN / G2_SPLIT);

  __shared__ __bf16 As[BM][ASTR];
  __shared__ __bf16 Bs[BN][ASTR];
  __shared__ int toks[BM];
  __shared__ float gts[BM];

  int tid = threadIdx.x;
  toks[tid] = (m0 + tid < cnt) ? tlist[e * NTOK + m0 + tid] : -1;
  gts[tid]  = (m0 + tid < cnt) ? gateE[e * NTOK + m0 + tid] : 0.f;
  __syncthreads();

  int lane = tid & 63, w = tid >> 6;
  int wm = w >> 1, wn = w & 1;
  int r16 = lane & 15, quad = lane >> 4;

  const float* w2e = w2 + (size_t)e * FFN * DM;
  f32x4 acc[8][2] = {};

  for (int kb = 0; kb < FFN / G2_SPLIT; kb += BK) {
    // A: gather h rows (bf16, k-contiguous)
#pragma unroll
    for (int it = 0; it < 8; it++) {
      int q = it * 256 + tid;
      int r = q >> 3, k8 = (q & 7) << 3;
      int tok = toks[r];
      bf16x8 v = (tok >= 0)
          ? *(const bf16x8*)(h + (size_t)tok * FFN + ksp + kb + k8)
          : zero8();
      *(bf16x8*)&As[r][k8] = v;
    }
    // B: fp32 [k][n] -> register 4x4 transpose -> bf16 [n][k] LDS
#pragma unroll
    for (int it = 0; it < 4; it++) {
      int k = ksp + kb + it * 16 + w * 4 + quad;
      const float4 t4 = *(const float4*)(w2e + (size_t)k * DM + n0 + r16 * 4);
      float vv[4] = {t4.x, t4.y, t4.z, t4.w};
      xpose4(vv, quad);
      bf16x4 o;
#pragma unroll
      for (int j = 0; j < 4; j++) o[j] = (__bf16)vv[j];
      *(bf16x4*)&Bs[r16 * 4 + quad][it * 16 + w * 4] = o;
    }
    __syncthreads();
#pragma unroll
    for (int kh = 0; kh < 2; kh++) {
      int ks = kh * 32 + quad * 8;
      bf16x8 b0 = *(const bf16x8*)&Bs[wn * 32 + r16][ks];
      bf16x8 b1 = *(const bf16x8*)&Bs[wn * 32 + 16 + r16][ks];
#pragma unroll
      for (int mf = 0; mf < 8; mf++) {
        bf16x8 a = *(const bf16x8*)&As[wm * 128 + mf * 16 + r16][ks];
        acc[mf][0] = __builtin_amdgcn_mfma_f32_16x16x32_bf16(a, b0, acc[mf][0], 0, 0, 0);
        acc[mf][1] = __builtin_amdgcn_mfma_f32_16x16x32_bf16(a, b1, acc[mf][1], 0, 0, 0);
      }
    }
    __syncthreads();
  }

#pragma unroll
  for (int mf = 0; mf < 8; mf++) {
#pragma unroll
    for (int i = 0; i < 4; i++) {
      int row = wm * 128 + mf * 16 + quad * 4 + i;
      int tok = toks[row];
      if (tok >= 0) {
        float g = gts[row];
        float* op = out + (size_t)tok * DM + n0 + wn * 32 + r16;
        __hip_atomic_fetch_add(op, acc[mf][0][i] * g,
                               __ATOMIC_RELAXED, __HIP_MEMORY_SCOPE_AGENT);
        __hip_atomic_fetch_add(op + 16, acc[mf][1][i] * g,
                               __ATOMIC_RELAXED, __HIP_MEMORY_SCOPE_AGENT);
      }
    }
  }
}

extern "C" void kernel_launch(void* const* d_in, const int* in_sizes, int n_in,
                              void* d_out, int out_size, void* d_ws, size_t ws_size,
                              hipStream_t stream) {
  const float* x    = (const float*)d_in[0];
  const int*   mask = (const int*)d_in[1];
  const float* rw   = (const float*)d_in[2];
  const float* w1   = (const float*)d_in[3];
  const float* w2   = (const float*)d_in[4];
  float* out = (float*)d_out;

  char* ws = (char*)d_ws;
  int*    counts = (int*)ws;                                   // 1 KB reserved
  int*    tlist  = (int*)(ws + 1024);                          // 64 KB
  float*  gateE  = (float*)(ws + 1024 + 65536);                // 64 KB
  __bf16* xg     = (__bf16*)(ws + 132096);                     // 32 MB compact bf16 x
  __bf16* h      = (__bf16*)(ws + 132096 + (size_t)NEXP * NTOK * DM * 2);  // 16 MB

  hipMemsetAsync(counts, 0, 1024, stream);
  hipMemsetAsync(out, 0, (size_t)out_size * sizeof(float), stream);

  router_gather<<<NTOK / 4, 256, 0, stream>>>(x, mask, rw, counts, tlist, gateE, xg);
  moe_gemm1<<<NEXP * 8 * 64, 256, 0, stream>>>(xg, w1, counts, tlist, h);
  moe_gemm2<<<G2_SPLIT * NEXP * 8 * 16, 256, 0, stream>>>(h, w2, counts, tlist, gateE, out);
}

// Round 4
// 159.215 us; speedup vs baseline: 1.3290x; 1.3290x over previous
//
#include <hip/hip_runtime.h>
#include <hip/hip_bf16.h>

#define NTOK 2048      // B*T
#define DM 1024
#define NEXP 8
#define FFN 4096
#define BM 64
#define BN 64
#define BK 64
#define ASTR 72        // LDS row stride (bf16): 144B, 16B-aligned, <=2-way read conflicts
#define MT1 8          // m-tiles covered (cap 512 tokens/expert; expected ~128)
#define G2_SPLIT 4

typedef __bf16 bf16x8 __attribute__((ext_vector_type(8)));
typedef __bf16 bf16x4 __attribute__((ext_vector_type(4)));
typedef float f32x4 __attribute__((ext_vector_type(4)));

__device__ __forceinline__ bf16x8 zero8() {
  bf16x8 z;
#pragma unroll
  for (int j = 0; j < 8; j++) z[j] = (__bf16)0.f;
  return z;
}

// 4x4 f32 transpose across lanes {l, l^16, l^32, l^48}.
__device__ __forceinline__ void xpose4(float v[4], int quad) {
  const bool b0 = quad & 1;
  const bool b1 = (quad & 2) != 0;
  float t;
  t = __shfl_xor(b0 ? v[0] : v[1], 16, 64); if (b0) v[0] = t; else v[1] = t;
  t = __shfl_xor(b0 ? v[2] : v[3], 16, 64); if (b0) v[2] = t; else v[3] = t;
  t = __shfl_xor(b1 ? v[0] : v[2], 32, 64); if (b1) v[0] = t; else v[2] = t;
  t = __shfl_xor(b1 ? v[1] : v[3], 32, 64); if (b1) v[1] = t; else v[3] = t;
}

// ---------------- router + bf16 compact gather ----------------
__global__ __launch_bounds__(256) void router_gather(
    const float* __restrict__ x, const int* __restrict__ mask,
    const float* __restrict__ rw, int* __restrict__ counts,
    int* __restrict__ tlist, float* __restrict__ gateE,
    __bf16* __restrict__ xg)
{
  int wid = threadIdx.x >> 6, lane = threadIdx.x & 63;
  int t = blockIdx.x * 4 + wid;

  const float* xr = x + (size_t)t * DM;
  float xv[16];
#pragma unroll
  for (int i = 0; i < 4; i++) {
    const float4 v = *(const float4*)(xr + lane * 16 + i * 4);
    xv[i * 4 + 0] = v.x; xv[i * 4 + 1] = v.y;
    xv[i * 4 + 2] = v.z; xv[i * 4 + 3] = v.w;
  }

  float acc[NEXP];
#pragma unroll
  for (int e = 0; e < NEXP; e++) {
    float a = 0.f;
    const float* rwe = rw + e * DM + lane * 16;
#pragma unroll
    for (int i = 0; i < 4; i++) {
      const float4 r = *(const float4*)(rwe + i * 4);
      a += xv[i*4+0]*r.x + xv[i*4+1]*r.y + xv[i*4+2]*r.z + xv[i*4+3]*r.w;
    }
    acc[e] = a;
  }
#pragma unroll
  for (int e = 0; e < NEXP; e++)
#pragma unroll
    for (int s = 1; s < 64; s <<= 1) acc[e] += __shfl_xor(acc[e], s, 64);

  int pack = -1;
  if (lane == 0 && mask[t] != 0) {
    float m = acc[0]; int am = 0;
#pragma unroll
    for (int e = 1; e < NEXP; e++) if (acc[e] > m) { m = acc[e]; am = e; }
    float s = 0.f;
#pragma unroll
    for (int e = 0; e < NEXP; e++) s += __expf(acc[e] - m);
    int slot = atomicAdd(&counts[am], 1);
    tlist[am * NTOK + slot] = t;
    gateE[am * NTOK + slot] = 1.0f / s;
    pack = am * NTOK + slot;
  }
  pack = __shfl(pack, 0, 64);
  if (pack >= 0) {
    __bf16* dst = xg + (size_t)pack * DM + lane * 16;
    bf16x8 o0, o1;
#pragma unroll
    for (int j = 0; j < 8; j++) {
      o0[j] = (__bf16)xv[j];
      o1[j] = (__bf16)xv[8 + j];
    }
    *(bf16x8*)dst = o0;
    *(bf16x8*)(dst + 8) = o1;
  }
}

// B staging: load fp32 [k][n] float4 -> register 4x4 lane transpose -> bf16 [n][k] LDS
#define STOREB(br, it) do {                                          \
    float vv[4] = {(br).x, (br).y, (br).z, (br).w};                  \
    xpose4(vv, quad);                                                \
    bf16x4 o;                                                        \
    o[0] = (__bf16)vv[0]; o[1] = (__bf16)vv[1];                      \
    o[2] = (__bf16)vv[2]; o[3] = (__bf16)vv[3];                      \
    *(bf16x4*)&Bs[(r16 << 2) + quad][(it) * 16 + (w << 2)] = o;      \
  } while (0)

// ---------------- GEMM1: h[tok] = relu(xg_e @ w1[e]) ----------------
__global__ __launch_bounds__(256) void moe_gemm1(
    const __bf16* __restrict__ xg, const float* __restrict__ w1,
    const int* __restrict__ counts, const int* __restrict__ tlist,
    __bf16* __restrict__ h)
{
  int bx = blockIdx.x;
  int nt = bx & 63, mt = (bx >> 6) & (MT1 - 1), e = bx >> 9;
  int cnt = counts[e];
  int m0 = mt * BM;
  if (m0 >= cnt) return;
  int n0 = nt * BN;

  __shared__ __bf16 As[BM][ASTR];
  __shared__ __bf16 Bs[BN][ASTR];
  __shared__ int toks[BM];

  int tid = threadIdx.x, lane = tid & 63, w = tid >> 6;
  int wm = w >> 1, wn = w & 1;
  int r16 = lane & 15, quad = lane >> 4;

  const __bf16* xge = xg + (size_t)e * NTOK * DM;
  const float*  w1e = w1 + (size_t)e * DM * FFN;

  // A: row ar = tid>>2 (0..63), k-offset ak = (tid&3)*16, two bf16x8 each
  int ar = tid >> 2;
  int ak = (tid & 3) << 4;
  bool av = (m0 + ar) < cnt;
  const __bf16* aptr = xge + (size_t)(m0 + ar) * DM + ak;
  // B: k = kb + it*16 + w*4 + quad, n = n0 + r16*4
  const float* bptr = w1e + (size_t)(w * 4 + quad) * FFN + n0 + (r16 << 2);

  bf16x8 a0r, a1r;
  float4 br0, br1, br2, br3;

#define LOADG1(kb) do {                                                   \
    a0r = av ? *(const bf16x8*)(aptr + (kb))     : zero8();               \
    a1r = av ? *(const bf16x8*)(aptr + (kb) + 8) : zero8();               \
    br0 = *(const float4*)(bptr + (size_t)((kb) +  0) * FFN);             \
    br1 = *(const float4*)(bptr + (size_t)((kb) + 16) * FFN);             \
    br2 = *(const float4*)(bptr + (size_t)((kb) + 32) * FFN);             \
    br3 = *(const float4*)(bptr + (size_t)((kb) + 48) * FFN);             \
  } while (0)

  f32x4 acc[2][2] = {};
  LOADG1(0);
  const int T = DM / BK;   // 16
  for (int t = 0; t < T; t++) {
    *(bf16x8*)&As[ar][ak]     = a0r;
    *(bf16x8*)&As[ar][ak + 8] = a1r;
    STOREB(br0, 0); STOREB(br1, 1); STOREB(br2, 2); STOREB(br3, 3);
    __syncthreads();
    if (t + 1 < T) LOADG1((t + 1) * BK);   // in flight during MFMA phase
#pragma unroll
    for (int kh = 0; kh < 2; kh++) {
      int ks = kh * 32 + (quad << 3);
      bf16x8 aA = *(const bf16x8*)&As[wm * 32 + r16][ks];
      bf16x8 aB = *(const bf16x8*)&As[wm * 32 + 16 + r16][ks];
      bf16x8 bA = *(const bf16x8*)&Bs[wn * 32 + r16][ks];
      bf16x8 bB = *(const bf16x8*)&Bs[wn * 32 + 16 + r16][ks];
      acc[0][0] = __builtin_amdgcn_mfma_f32_16x16x32_bf16(aA, bA, acc[0][0], 0, 0, 0);
      acc[0][1] = __builtin_amdgcn_mfma_f32_16x16x32_bf16(aA, bB, acc[0][1], 0, 0, 0);
      acc[1][0] = __builtin_amdgcn_mfma_f32_16x16x32_bf16(aB, bA, acc[1][0], 0, 0, 0);
      acc[1][1] = __builtin_amdgcn_mfma_f32_16x16x32_bf16(aB, bB, acc[1][1], 0, 0, 0);
    }
    __syncthreads();
  }
#undef LOADG1

  if (tid < BM) toks[tid] = (m0 + tid < cnt) ? tlist[e * NTOK + m0 + tid] : -1;
  __syncthreads();

#pragma unroll
  for (int mf = 0; mf < 2; mf++) {
#pragma unroll
    for (int i = 0; i < 4; i++) {
      int row = wm * 32 + mf * 16 + (quad << 2) + i;
      int tok = toks[row];
      if (tok >= 0) {
        __bf16* hp = h + (size_t)tok * FFN + n0 + wn * 32 + r16;
        hp[0]  = (__bf16)fmaxf(acc[mf][0][i], 0.f);
        hp[16] = (__bf16)fmaxf(acc[mf][1][i], 0.f);
      }
    }
  }
}

// ------- GEMM2 (split-K): out[tok] += (h_e @ w2[e]) * gate ----------
__global__ __launch_bounds__(256) void moe_gemm2(
    const __bf16* __restrict__ h, const float* __restrict__ w2,
    const int* __restrict__ counts, const int* __restrict__ tlist,
    const float* __restrict__ gateE, float* __restrict__ out)
{
  int bx = blockIdx.x;
  int nt = bx & 15, mt = (bx >> 4) & (MT1 - 1), e = (bx >> 7) & 7, sp = bx >> 10;
  int cnt = counts[e];
  int m0 = mt * BM;
  if (m0 >= cnt) return;
  int n0 = nt * BN;
  int ksp = sp * (FFN / G2_SPLIT);

  __shared__ __bf16 As[BM][ASTR];
  __shared__ __bf16 Bs[BN][ASTR];
  __shared__ int toks[BM];
  __shared__ float gts[BM];

  int tid = threadIdx.x, lane = tid & 63, w = tid >> 6;
  int wm = w >> 1, wn = w & 1;
  int r16 = lane & 15, quad = lane >> 4;

  if (tid < BM) {
    bool v = (m0 + tid) < cnt;
    toks[tid] = v ? tlist[e * NTOK + m0 + tid] : -1;
    gts[tid]  = v ? gateE[e * NTOK + m0 + tid] : 0.f;
  }
  __syncthreads();

  const float* w2e = w2 + (size_t)e * FFN * DM;

  int ar = tid >> 2;
  int ak = (tid & 3) << 4;
  int tok0 = toks[ar];
  bool av = tok0 >= 0;
  const __bf16* aptr = h + (size_t)(av ? tok0 : 0) * FFN + ak;
  const float* bptr = w2e + (size_t)(w * 4 + quad) * DM + n0 + (r16 << 2);

  bf16x8 a0r, a1r;
  float4 br0, br1, br2, br3;

#define LOADG2(kb) do {                                                   \
    a0r = av ? *(const bf16x8*)(aptr + (kb))     : zero8();               \
    a1r = av ? *(const bf16x8*)(aptr + (kb) + 8) : zero8();               \
    br0 = *(const float4*)(bptr + (size_t)((kb) +  0) * DM);              \
    br1 = *(const float4*)(bptr + (size_t)((kb) + 16) * DM);              \
    br2 = *(const float4*)(bptr + (size_t)((kb) + 32) * DM);              \
    br3 = *(const float4*)(bptr + (size_t)((kb) + 48) * DM);              \
  } while (0)

  f32x4 acc[2][2] = {};
  LOADG2(ksp);
  const int T = (FFN / G2_SPLIT) / BK;   // 16
  for (int t = 0; t < T; t++) {
    *(bf16x8*)&As[ar][ak]     = a0r;
    *(bf16x8*)&As[ar][ak + 8] = a1r;
    STOREB(br0, 0); STOREB(br1, 1); STOREB(br2, 2); STOREB(br3, 3);
    __syncthreads();
    if (t + 1 < T) LOADG2(ksp + (t + 1) * BK);
#pragma unroll
    for (int kh = 0; kh < 2; kh++) {
      int ks = kh * 32 + (quad << 3);
      bf16x8 aA = *(const bf16x8*)&As[wm * 32 + r16][ks];
      bf16x8 aB = *(const bf16x8*)&As[wm * 32 + 16 + r16][ks];
      bf16x8 bA = *(const bf16x8*)&Bs[wn * 32 + r16][ks];
      bf16x8 bB = *(const bf16x8*)&Bs[wn * 32 + 16 + r16][ks];
      acc[0][0] = __builtin_amdgcn_mfma_f32_16x16x32_bf16(aA, bA, acc[0][0], 0, 0, 0);
      acc[0][1] = __builtin_amdgcn_mfma_f32_16x16x32_bf16(aA, bB, acc[0][1], 0, 0, 0);
      acc[1][0] = __builtin_amdgcn_mfma_f32_16x16x32_bf16(aB, bA, acc[1][0], 0, 0, 0);
      acc[1][1] = __builtin_amdgcn_mfma_f32_16x16x32_bf16(aB, bB, acc[1][1], 0, 0, 0);
    }
    __syncthreads();
  }
#undef LOADG2

#pragma unroll
  for (int mf = 0; mf < 2; mf++) {
#pragma unroll
    for (int i = 0; i < 4; i++) {
      int row = wm * 32 + mf * 16 + (quad << 2) + i;
      int tok = toks[row];
      if (tok >= 0) {
        float g = gts[row];
        float* op = out + (size_t)tok * DM + n0 + wn * 32 + r16;
        __hip_atomic_fetch_add(op, acc[mf][0][i] * g,
                               __ATOMIC_RELAXED, __HIP_MEMORY_SCOPE_AGENT);
        __hip_atomic_fetch_add(op + 16, acc[mf][1][i] * g,
                               __ATOMIC_RELAXED, __HIP_MEMORY_SCOPE_AGENT);
      }
    }
  }
}

extern "C" void kernel_launch(void* const* d_in, const int* in_sizes, int n_in,
                              void* d_out, int out_size, void* d_ws, size_t ws_size,
                              hipStream_t stream) {
  const float* x    = (const float*)d_in[0];
  const int*   mask = (const int*)d_in[1];
  const float* rw   = (const float*)d_in[2];
  const float* w1   = (const float*)d_in[3];
  const float* w2   = (const float*)d_in[4];
  float* out = (float*)d_out;

  char* ws = (char*)d_ws;
  int*    counts = (int*)ws;                                   // 1 KB
  int*    tlist  = (int*)(ws + 1024);                          // 64 KB
  float*  gateE  = (float*)(ws + 1024 + 65536);                // 64 KB
  __bf16* xg     = (__bf16*)(ws + 132096);                     // 32 MB compact bf16 x
  __bf16* h      = (__bf16*)(ws + 132096 + (size_t)NEXP * NTOK * DM * 2);  // 16 MB

  hipMemsetAsync(counts, 0, 1024, stream);
  hipMemsetAsync(out, 0, (size_t)out_size * sizeof(float), stream);

  router_gather<<<NTOK / 4, 256, 0, stream>>>(x, mask, rw, counts, tlist, gateE, xg);
  moe_gemm1<<<NEXP * MT1 * (FFN / BN), 256, 0, stream>>>(xg, w1, counts, tlist, h);
  moe_gemm2<<<G2_SPLIT * NEXP * MT1 * (DM / BN), 256, 0, stream>>>(
      h, w2, counts, tlist, gateE, out);
}